// Round 4
// baseline (314.924 us; speedup 1.0000x reference)
//
#include <hip/hip_runtime.h>
#include <math.h>

// SuperLoss elementwise (LAM=1, TAU=0):
//   il  = BCE_with_logits(pr, gt) = max(pr,0) - pr*gt + log1p(exp(-|pr|))  (>= 0)
//   y   = il/2   (BETA0 clamp never fires since il >= 0)
//   w   = LambertW(y), principal branch
//   out = sigma*il + log(sigma)^2 = 2w + w^2 = (w+1)^2 - 1   [w*e^w = y identity]
//
// Lambert W, exp-free refinement (round 1; verified: VALUBusy 45% -> 20-24%):
//   w0 = log1p(y)  =>  e^{w0} = 1+y EXACTLY  => Halley step 1 needs no exp.
//   Step 2: e^{w1} = (1+y)*e^{w1-w0}, delta in [-0.6,0] -> 4-term Taylor,
//   then one Newton step. Trans budget/elem: exp + 2 log + 2 rcp = 5.
//
// Memory path history:
//   r0: 4 elem/thread, plain stores            -> 112 us, FETCH 131 MB
//   r2: 8 elem/thread STRIDE-2 + NT stores     -> 130 us, WRITE +11% (partial
//       lines: NT + uncoalesced lanes), FETCH unchanged
//   r3: 8 elem/thread BLOCK-CHUNKED (unit-stride), plain stores
//                                              -> 112 us, WRITE exactly 131072
//   Finding: time invariant to VALU work (45%->24% busy) and MLP depth; all
//   pipes underutilized; bound by HBM traffic volume (262 MB @ ~2.4 TB/s).
//   FETCH == half of inputs: the 134 MB output stream write-allocates in the
//   256 MB L3 and evicts half the 268 MB input set (steady state 134+~120).
//
// THIS ROUND (single change): NT stores on the now-coalesced layout. Wave
// stores are contiguous 1 KB blocks -> full lines even with NT, so no WRITE
// inflation; output no longer allocates in L3 -> inputs become ~L3-resident
// -> FETCH_SIZE collapses -> less HBM round-trip traffic.

typedef float f32x4 __attribute__((ext_vector_type(4)));

__device__ __forceinline__ float superloss_elem(float pr, float gt) {
    const float LOG2E = 1.44269504f;
    const float LN2   = 0.69314718f;

    // Stable BCE with logits (base-2 hardware trans ops)
    float t  = __builtin_amdgcn_exp2f(-fabsf(pr) * LOG2E);   // e^{-|pr|}
    float lg = __builtin_amdgcn_logf(1.0f + t);              // log2(1+t)
    float il = __fmaf_rn(-pr, gt, fmaxf(pr, 0.0f));
    il = __fmaf_rn(LN2, lg, il);                             // + log1p(e^{-|pr|})

    float y   = 0.5f * il;                                   // y >= 0
    float opy = 1.0f + y;                                    // = e^{w0}, exact
    float w0  = LN2 * __builtin_amdgcn_logf(opy);            // log1p(y)

    // Halley step 1 (exp-free: e^{w0} = opy)
    float f   = __fmaf_rn(w0, opy, -y);
    float wp1 = w0 + 1.0f;
    float num = 2.0f * f * wp1;
    float den = __fmaf_rn(opy + opy, wp1 * wp1, -(w0 + 2.0f) * f);
    float w1  = __fmaf_rn(-num, __builtin_amdgcn_rcpf(den), w0);

    // e^{w1} = opy * e^{nd}, nd = w1 - w0 in [-0.6, 0]; 4th-order Taylor
    float nd = w1 - w0;
    float p  = __fmaf_rn(nd, 0.041666668f, 0.16666667f);
    p = __fmaf_rn(nd, p, 0.5f);
    p = __fmaf_rn(nd, p, 1.0f);
    p = __fmaf_rn(nd, p, 1.0f);
    float e = opy * p;

    // Newton step
    float f2 = __fmaf_rn(w1, e, -y);
    float d2 = e * (w1 + 1.0f);
    float w  = __fmaf_rn(-f2, __builtin_amdgcn_rcpf(d2), w1);

    float u = w + 1.0f;
    return __fmaf_rn(u, u, -1.0f);                           // w*(w+2)
}

__device__ __forceinline__ f32x4 superloss_vec(f32x4 p, f32x4 g) {
    f32x4 o;
    o.x = superloss_elem(p.x, g.x);
    o.y = superloss_elem(p.y, g.y);
    o.z = superloss_elem(p.z, g.z);
    o.w = superloss_elem(p.w, g.w);
    return o;
}

__global__ __launch_bounds__(256) void superloss_vec8(const f32x4* __restrict__ pr,
                                                      const f32x4* __restrict__ gt,
                                                      f32x4* __restrict__ out,
                                                      int n4) {
    int i0 = blockIdx.x * 512 + threadIdx.x;  // 512 float4s per block
    int i1 = i0 + 256;
    if (i1 < n4) {
        // 4 unit-stride dwordx4 loads in flight before compute
        f32x4 p0 = pr[i0];
        f32x4 p1 = pr[i1];
        f32x4 g0 = gt[i0];
        f32x4 g1 = gt[i1];
        f32x4 o0 = superloss_vec(p0, g0);
        f32x4 o1 = superloss_vec(p1, g1);
        // NT: full-line streaming stores (1 KB contiguous per wave store),
        // don't allocate output in L3 -> keep inputs resident.
        __builtin_nontemporal_store(o0, out + i0);
        __builtin_nontemporal_store(o1, out + i1);
    } else if (i0 < n4) {
        f32x4 o = superloss_vec(pr[i0], gt[i0]);
        __builtin_nontemporal_store(o, out + i0);
    }
}

__global__ __launch_bounds__(256) void superloss_scalar(const float* __restrict__ pr,
                                                        const float* __restrict__ gt,
                                                        float* __restrict__ out,
                                                        int base, int n) {
    int i = base + blockIdx.x * blockDim.x + threadIdx.x;
    if (i < n) {
        out[i] = superloss_elem(pr[i], gt[i]);
    }
}

extern "C" void kernel_launch(void* const* d_in, const int* in_sizes, int n_in,
                              void* d_out, int out_size, void* d_ws, size_t ws_size,
                              hipStream_t stream) {
    const float* pr = (const float*)d_in[0];
    const float* gt = (const float*)d_in[1];
    float* out = (float*)d_out;
    int n = in_sizes[0];

    int n4 = n / 4;
    if (n4 > 0) {
        int blocks = (n4 + 511) / 512;  // 512 float4s (2048 elems) per block
        superloss_vec8<<<blocks, 256, 0, stream>>>((const f32x4*)pr, (const f32x4*)gt,
                                                   (f32x4*)out, n4);
    }
    int rem = n - n4 * 4;
    if (rem > 0) {
        superloss_scalar<<<1, 256, 0, stream>>>(pr, gt, out, n4 * 4, n);
    }
}

// Round 5
// 307.967 us; speedup vs baseline: 1.0226x; 1.0226x over previous
//
#include <hip/hip_runtime.h>
#include <math.h>

// SuperLoss elementwise (LAM=1, TAU=0):
//   il  = BCE_with_logits(pr, gt) = max(pr,0) - pr*gt + log1p(exp(-|pr|))  (>= 0)
//   y   = il/2;  w = LambertW(y);  out = sigma*il + log(sigma)^2 = w*(w+2)
//   [via w*e^w = y => sigma = e^{-w} = w/y]
//
// Lambert W, exp-free refinement (r1; verified: VALUBusy 45% -> 21-24%):
//   w0 = log1p(y) => e^{w0} = 1+y EXACTLY => Halley step 1 needs no exp.
//   Step 2: e^{w1} = (1+y)*e^{w1-w0}, delta in [-0.6,0] -> 4-term Taylor,
//   then one Newton step. Trans budget/elem: exp + 2 log + 2 rcp = 5.
//
// Memory-path history (all measured):
//   r0: 4 e/t plain                 112 us  FETCH 131098  WRITE 131072
//   r2: 8 e/t stride-2 + NT         130 us  WRITE +11% (partial lines)
//   r3: 8 e/t chunked  plain        112 us  byte counts exact
//   r4: 8 e/t chunked  + NT         126 us  FETCH UNCHANGED -> NT refuted:
//       store policy has zero effect on input L3 residency; NT path slower.
//   Invariants: FETCH pinned at 134 MB (L3 serves the other half of inputs),
//   time invariant to VALU work, no pipe saturated. Per-wave round trip
//   ~23K cycles >> 900 cy HBM latency => latency/queueing bound, low MLP
//   duty cycle (load->wait->long compute->store).
//
// THIS ROUND (single change): 16 elem/thread, 8 dwordx4 loads in flight
// (8 KB/wave outstanding, 2x r3), unit-stride chunked at +256 float4s.
// Compiler's counted vmcnt overlaps chunk-0 compute with chunks 1-3 in
// flight. Plain stores (NT reverted).

typedef float f32x4 __attribute__((ext_vector_type(4)));

__device__ __forceinline__ float superloss_elem(float pr, float gt) {
    const float LOG2E = 1.44269504f;
    const float LN2   = 0.69314718f;

    // Stable BCE with logits (base-2 hardware trans ops)
    float t  = __builtin_amdgcn_exp2f(-fabsf(pr) * LOG2E);   // e^{-|pr|}
    float lg = __builtin_amdgcn_logf(1.0f + t);              // log2(1+t)
    float il = __fmaf_rn(-pr, gt, fmaxf(pr, 0.0f));
    il = __fmaf_rn(LN2, lg, il);                             // + log1p(e^{-|pr|})

    float y   = 0.5f * il;                                   // y >= 0
    float opy = 1.0f + y;                                    // = e^{w0}, exact
    float w0  = LN2 * __builtin_amdgcn_logf(opy);            // log1p(y)

    // Halley step 1 (exp-free: e^{w0} = opy)
    float f   = __fmaf_rn(w0, opy, -y);
    float wp1 = w0 + 1.0f;
    float num = 2.0f * f * wp1;
    float den = __fmaf_rn(opy + opy, wp1 * wp1, -(w0 + 2.0f) * f);
    float w1  = __fmaf_rn(-num, __builtin_amdgcn_rcpf(den), w0);

    // e^{w1} = opy * e^{nd}, nd = w1 - w0 in [-0.6, 0]; 4th-order Taylor
    float nd = w1 - w0;
    float p  = __fmaf_rn(nd, 0.041666668f, 0.16666667f);
    p = __fmaf_rn(nd, p, 0.5f);
    p = __fmaf_rn(nd, p, 1.0f);
    p = __fmaf_rn(nd, p, 1.0f);
    float e = opy * p;

    // Newton step
    float f2 = __fmaf_rn(w1, e, -y);
    float d2 = e * (w1 + 1.0f);
    float w  = __fmaf_rn(-f2, __builtin_amdgcn_rcpf(d2), w1);

    float u = w + 1.0f;
    return __fmaf_rn(u, u, -1.0f);                           // w*(w+2)
}

__device__ __forceinline__ f32x4 superloss_vec(f32x4 p, f32x4 g) {
    f32x4 o;
    o.x = superloss_elem(p.x, g.x);
    o.y = superloss_elem(p.y, g.y);
    o.z = superloss_elem(p.z, g.z);
    o.w = superloss_elem(p.w, g.w);
    return o;
}

__global__ __launch_bounds__(256) void superloss_vec16(const f32x4* __restrict__ pr,
                                                       const f32x4* __restrict__ gt,
                                                       f32x4* __restrict__ out,
                                                       int n4) {
    int i0 = blockIdx.x * 1024 + threadIdx.x;  // 1024 float4s per block
    int i1 = i0 + 256;
    int i2 = i0 + 512;
    int i3 = i0 + 768;
    if (i3 < n4) {
        // 8 unit-stride dwordx4 loads issued back-to-back (8 KB/wave in
        // flight); compiler's counted vmcnt lets chunk-0 compute start
        // while chunks 1-3 are still in the memory system.
        f32x4 p0 = pr[i0];
        f32x4 g0 = gt[i0];
        f32x4 p1 = pr[i1];
        f32x4 g1 = gt[i1];
        f32x4 p2 = pr[i2];
        f32x4 g2 = gt[i2];
        f32x4 p3 = pr[i3];
        f32x4 g3 = gt[i3];
        out[i0] = superloss_vec(p0, g0);
        out[i1] = superloss_vec(p1, g1);
        out[i2] = superloss_vec(p2, g2);
        out[i3] = superloss_vec(p3, g3);
    } else {
        if (i0 < n4) out[i0] = superloss_vec(pr[i0], gt[i0]);
        if (i1 < n4) out[i1] = superloss_vec(pr[i1], gt[i1]);
        if (i2 < n4) out[i2] = superloss_vec(pr[i2], gt[i2]);
    }
}

__global__ __launch_bounds__(256) void superloss_scalar(const float* __restrict__ pr,
                                                        const float* __restrict__ gt,
                                                        float* __restrict__ out,
                                                        int base, int n) {
    int i = base + blockIdx.x * blockDim.x + threadIdx.x;
    if (i < n) {
        out[i] = superloss_elem(pr[i], gt[i]);
    }
}

extern "C" void kernel_launch(void* const* d_in, const int* in_sizes, int n_in,
                              void* d_out, int out_size, void* d_ws, size_t ws_size,
                              hipStream_t stream) {
    const float* pr = (const float*)d_in[0];
    const float* gt = (const float*)d_in[1];
    float* out = (float*)d_out;
    int n = in_sizes[0];

    int n4 = n / 4;
    if (n4 > 0) {
        int blocks = (n4 + 1023) / 1024;  // 1024 float4s (4096 elems) per block
        superloss_vec16<<<blocks, 256, 0, stream>>>((const f32x4*)pr, (const f32x4*)gt,
                                                    (f32x4*)out, n4);
    }
    int rem = n - n4 * 4;
    if (rem > 0) {
        superloss_scalar<<<1, 256, 0, stream>>>(pr, gt, out, n4 * 4, n);
    }
}